// Round 14
// baseline (5218.728 us; speedup 1.0000x reference)
//
#include <hip/hip_runtime.h>
#include <hip/hip_bf16.h>

#define NFEAT   128
#define NATTRI  500
#define NNODES  100000
#define NEDGES  3200000
#define HCAP    1000000   // flat nz list capacity (expected ~500K)
#define HSLOTS  32        // per-node slot capacity (P(nnz>=32) ~ 1e-14)

typedef __hip_bfloat16 bf16;
typedef __attribute__((ext_vector_type(8))) short short8v;
typedef __attribute__((ext_vector_type(4))) float f32x4;

__device__ __forceinline__ float sigmoidf_(float x) { return 1.0f / (1.0f + __expf(-x)); }
__device__ __forceinline__ float b2f_(short u) {
  return __uint_as_float(((unsigned)(unsigned short)u) << 16);
}

// ---------------------------------------------------------------------------
// f32 -> bf16 cast, 4 elems/thread.
// ---------------------------------------------------------------------------
__global__ __launch_bounds__(256) void k_cvt_bf(const float* __restrict__ src,
                                                bf16* __restrict__ dst, int n)
{
  int i = (blockIdx.x * 256 + threadIdx.x) * 4;
  if (i >= n) return;
  float4 v = *(const float4*)&src[i];
  __hip_bfloat162 a, b;
  a.x = __float2bfloat16(v.x); a.y = __float2bfloat16(v.y);
  b.x = __float2bfloat16(v.z); b.y = __float2bfloat16(v.w);
  *(__hip_bfloat162*)&dst[i]     = a;
  *(__hip_bfloat162*)&dst[i + 2] = b;
}

// ---------------------------------------------------------------------------
// Small conversions: W0t[128][256], W1t[128][128], attr_bf[500][128].
// ---------------------------------------------------------------------------
__global__ __launch_bounds__(256) void k_cvt_small(
    const float* __restrict__ W0, const float* __restrict__ W1,
    const float* __restrict__ emb_attr,
    bf16* __restrict__ W0t, bf16* __restrict__ W1t, bf16* __restrict__ attrb)
{
  int i = blockIdx.x * 256 + threadIdx.x;
  if (i < 32768) {
    int n = i >> 8, k = i & 255;
    W0t[i] = __float2bfloat16(W0[k * 128 + n]);
  } else if (i < 49152) {
    int j = i - 32768;
    int n = j >> 7, k = j & 127;
    W1t[j] = __float2bfloat16(W1[k * 128 + n]);
  } else if (i < 113152) {
    int j = i - 49152;
    attrb[j] = __float2bfloat16(emb_attr[j]);
  }
}

// ---------------------------------------------------------------------------
// Single-pass H nonzero extraction: per-node slots + flat list.
// ---------------------------------------------------------------------------
__global__ __launch_bounds__(256) void k_hnz_single(
    const float* __restrict__ H, int* __restrict__ hcnt,
    int* __restrict__ hslot, int* __restrict__ hattr,
    int* __restrict__ hnode, int* __restrict__ nz_ctr)
{
  const int a   = blockIdx.y;
  const int off = blockIdx.x * 1024 + threadIdx.x * 4;
  float hv[4] = {0.f, 0.f, 0.f, 0.f};
  if (off + 3 < NNODES) {
    float4 h4 = *(const float4*)&H[(size_t)a * NNODES + off];
    hv[0] = h4.x; hv[1] = h4.y; hv[2] = h4.z; hv[3] = h4.w;
  } else {
    for (int j = 0; j < 4; ++j) {
      int n = off + j;
      if (n < NNODES) hv[j] = H[(size_t)a * NNODES + n];
    }
  }
  #pragma unroll
  for (int j = 0; j < 4; ++j) {
    if (hv[j] > 0.5f) {
      int n = off + j;
      int slot = atomicAdd(&hcnt[n], 1);
      if (slot < HSLOTS) hslot[n * HSLOTS + slot] = a;
      int pos = atomicAdd(nz_ctr, 1);        // wave-aggregated by compiler
      if (pos < HCAP) { hattr[pos] = a; hnode[pos] = n; }
    }
  }
}

// ---------------------------------------------------------------------------
// Hacc[n] = sum of emb_attr rows over H-nonzero slots -> bf16.
// ---------------------------------------------------------------------------
__global__ __launch_bounds__(256) void k_hacc_sparse(
    const int* __restrict__ hcnt, const int* __restrict__ hslot,
    const float* __restrict__ emb_attr, bf16* __restrict__ Haccb)
{
  int n = blockIdx.x * 4 + (threadIdx.x >> 6);
  if (n >= NNODES) return;
  int lane = threadIdx.x & 63;
  int cnt = min(hcnt[n], HSLOTS);
  int f = lane * 2;
  float ax = 0.f, ay = 0.f;
  for (int i = 0; i < cnt; ++i) {
    int a = hslot[n * HSLOTS + i];           // wave-uniform broadcast
    float2 v = *(const float2*)&emb_attr[a * 128 + f];
    ax += v.x; ay += v.y;
  }
  __hip_bfloat162 o;
  o.x = __float2bfloat16(ax); o.y = __float2bfloat16(ay);
  *(__hip_bfloat162*)&Haccb[(size_t)n * 128 + f] = o;
}

// ---------------------------------------------------------------------------
// MFMA GEMM: Y[n][c] = Xcat@W + b, bf16 out. 128x128 tile, 4 waves.
// ---------------------------------------------------------------------------
template<int KTOT>
__global__ __launch_bounds__(256) void k_gemm_mfma(
    const bf16* __restrict__ X0, const bf16* __restrict__ X1,
    const bf16* __restrict__ Wt, const float* __restrict__ bias,
    bf16* __restrict__ Y)
{
  __shared__ __align__(16) short sX[128 * 72];
  __shared__ __align__(16) short sW[128 * 72];
  const int t = threadIdx.x;
  const int w = t >> 6, l = t & 63;
  const int lrow = l & 15, lk = (l >> 4) * 8;
  const int r0 = blockIdx.x * 128;

  f32x4 acc[2][8];
  #pragma unroll
  for (int m2 = 0; m2 < 2; ++m2)
    #pragma unroll
    for (int nf = 0; nf < 8; ++nf)
      acc[m2][nf] = (f32x4){0.f, 0.f, 0.f, 0.f};

  for (int kc = 0; kc < KTOT; kc += 64) {
    __syncthreads();
    {
      int row = t >> 1, ks = (t & 1) * 32;
      int n = r0 + row;
      int gk = kc + ks;
      const bf16* src = X0; int k0 = gk;
      if (KTOT == 256 && gk >= 128) { src = X1; k0 = gk - 128; }
      short* d = &sX[row * 72 + ks];
      if (n < NNODES) {
        const short* p = (const short*)&src[(size_t)n * 128 + k0];
        #pragma unroll
        for (int i = 0; i < 4; ++i) *(short8v*)&d[i * 8] = *(const short8v*)&p[i * 8];
      } else {
        short8v z = (short8v){0,0,0,0,0,0,0,0};
        #pragma unroll
        for (int i = 0; i < 4; ++i) *(short8v*)&d[i * 8] = z;
      }
    }
    {
      int nrow = t >> 1, ks = (t & 1) * 32;
      const short* p = (const short*)&Wt[(size_t)nrow * KTOT + kc + ks];
      short* d = &sW[nrow * 72 + ks];
      #pragma unroll
      for (int i = 0; i < 4; ++i) *(short8v*)&d[i * 8] = *(const short8v*)&p[i * 8];
    }
    __syncthreads();
    #pragma unroll
    for (int kf = 0; kf < 2; ++kf) {
      short8v a0 = *(const short8v*)&sX[(w * 32 +      lrow) * 72 + kf * 32 + lk];
      short8v a1 = *(const short8v*)&sX[(w * 32 + 16 + lrow) * 72 + kf * 32 + lk];
      #pragma unroll
      for (int nf = 0; nf < 8; ++nf) {
        short8v b = *(const short8v*)&sW[(nf * 16 + lrow) * 72 + kf * 32 + lk];
        acc[0][nf] = __builtin_amdgcn_mfma_f32_16x16x32_bf16(a0, b, acc[0][nf], 0, 0, 0);
        acc[1][nf] = __builtin_amdgcn_mfma_f32_16x16x32_bf16(a1, b, acc[1][nf], 0, 0, 0);
      }
    }
  }
  #pragma unroll
  for (int m2 = 0; m2 < 2; ++m2) {
    int rbase = r0 + w * 32 + m2 * 16 + (l >> 4) * 4;
    #pragma unroll
    for (int nf = 0; nf < 8; ++nf) {
      int col = nf * 16 + lrow;
      float bv = bias[col];
      #pragma unroll
      for (int ri = 0; ri < 4; ++ri) {
        int grow = rbase + ri;
        if (grow < NNODES)
          Y[(size_t)grow * 128 + col] = __float2bfloat16(acc[m2][nf][ri] + bv);
      }
    }
  }
}

// ---------------------------------------------------------------------------
// MFMA loss base: sum 0.1*sigmoid(emb_node @ emb_attr^T)^2 over all pairs.
// ---------------------------------------------------------------------------
__global__ __launch_bounds__(256) void k_loss_mfma(
    const bf16* __restrict__ Xb, const bf16* __restrict__ Ab,
    float* __restrict__ loss_acc)
{
  __shared__ __align__(16) short sX[128 * 72];
  __shared__ __align__(16) short sW[128 * 72];
  __shared__ float red[4];
  const int t = threadIdx.x;
  const int w = t >> 6, l = t & 63;
  const int lrow = l & 15, lk = (l >> 4) * 8;
  const int r0 = blockIdx.x * 128;
  const int a0 = blockIdx.y * 128;

  f32x4 acc[2][8];
  #pragma unroll
  for (int m2 = 0; m2 < 2; ++m2)
    #pragma unroll
    for (int nf = 0; nf < 8; ++nf)
      acc[m2][nf] = (f32x4){0.f, 0.f, 0.f, 0.f};

  for (int kc = 0; kc < 128; kc += 64) {
    __syncthreads();
    {
      int row = t >> 1, ks = (t & 1) * 32;
      int n = r0 + row;
      short* d = &sX[row * 72 + ks];
      if (n < NNODES) {
        const short* p = (const short*)&Xb[(size_t)n * 128 + kc + ks];
        #pragma unroll
        for (int i = 0; i < 4; ++i) *(short8v*)&d[i * 8] = *(const short8v*)&p[i * 8];
      } else {
        short8v z = (short8v){0,0,0,0,0,0,0,0};
        #pragma unroll
        for (int i = 0; i < 4; ++i) *(short8v*)&d[i * 8] = z;
      }
    }
    {
      int nrow = t >> 1, ks = (t & 1) * 32;
      int a = a0 + nrow;
      short* d = &sW[nrow * 72 + ks];
      if (a < NATTRI) {
        const short* p = (const short*)&Ab[(size_t)a * 128 + kc + ks];
        #pragma unroll
        for (int i = 0; i < 4; ++i) *(short8v*)&d[i * 8] = *(const short8v*)&p[i * 8];
      } else {
        short8v z = (short8v){0,0,0,0,0,0,0,0};
        #pragma unroll
        for (int i = 0; i < 4; ++i) *(short8v*)&d[i * 8] = z;
      }
    }
    __syncthreads();
    #pragma unroll
    for (int kf = 0; kf < 2; ++kf) {
      short8v av0 = *(const short8v*)&sX[(w * 32 +      lrow) * 72 + kf * 32 + lk];
      short8v av1 = *(const short8v*)&sX[(w * 32 + 16 + lrow) * 72 + kf * 32 + lk];
      #pragma unroll
      for (int nf = 0; nf < 8; ++nf) {
        short8v b = *(const short8v*)&sW[(nf * 16 + lrow) * 72 + kf * 32 + lk];
        acc[0][nf] = __builtin_amdgcn_mfma_f32_16x16x32_bf16(av0, b, acc[0][nf], 0, 0, 0);
        acc[1][nf] = __builtin_amdgcn_mfma_f32_16x16x32_bf16(av1, b, acc[1][nf], 0, 0, 0);
      }
    }
  }
  float lacc = 0.f;
  #pragma unroll
  for (int m2 = 0; m2 < 2; ++m2) {
    int rbase = r0 + w * 32 + m2 * 16 + (l >> 4) * 4;
    #pragma unroll
    for (int nf = 0; nf < 8; ++nf) {
      int col = a0 + nf * 16 + lrow;
      if (col < NATTRI) {
        #pragma unroll
        for (int ri = 0; ri < 4; ++ri) {
          int grow = rbase + ri;
          if (grow < NNODES) {
            float s = sigmoidf_(acc[m2][nf][ri]);
            lacc += 0.1f * s * s;
          }
        }
      }
    }
  }
  for (int off = 32; off; off >>= 1) lacc += __shfl_xor(lacc, off, 64);
  if (l == 0) red[w] = lacc;
  __syncthreads();
  if (t == 0) atomicAdd(loss_acc, red[0] + red[1] + red[2] + red[3]);
}

// ---------------------------------------------------------------------------
// Flat loss correction: wave per nz entry, grid-stride.
// ---------------------------------------------------------------------------
__global__ __launch_bounds__(256) void k_loss_corr_flat(
    const int* __restrict__ hnode, const int* __restrict__ hattr,
    const int* __restrict__ nz_ctr,
    const float* __restrict__ emb_attr, const float* __restrict__ emb_node,
    float* __restrict__ loss_acc)
{
  __shared__ float red[4];
  const int total = min(*nz_ctr, HCAP);
  const int lane = threadIdx.x & 63;
  const int wv = (blockIdx.x * 256 + threadIdx.x) >> 6;
  const int nw = gridDim.x * 4;
  float part = 0.f;
  for (int i = wv; i < total; i += nw) {
    int n = hnode[i];
    int a = hattr[i];
    float2 x = *(const float2*)&emb_node[(size_t)n * 128 + lane * 2];
    float2 w = *(const float2*)&emb_attr[a * 128 + lane * 2];
    float d = x.x * w.x + x.y * w.y;
    for (int off = 32; off; off >>= 1) d += __shfl_xor(d, off, 64);
    if (lane == 0) {
      float sg = sigmoidf_(d);
      float om = 1.f - sg;
      part += 2.0f * om * om - 0.1f * sg * sg;
    }
  }
  if (lane == 0) red[threadIdx.x >> 6] = part;
  __syncthreads();
  if (threadIdx.x == 0) atomicAdd(loss_acc, red[0] + red[1] + red[2] + red[3]);
}

// ---------------------------------------------------------------------------
// Edge CSR build: hist + 3-phase parallel scan + scatter
// ---------------------------------------------------------------------------
__global__ __launch_bounds__(256) void k_hist(const int* __restrict__ g_row,
                                              int* __restrict__ deg) {
  int e = blockIdx.x * 256 + threadIdx.x;
  if (e < NEDGES) atomicAdd(&deg[g_row[e]], 1);
}

__global__ __launch_bounds__(256) void k_scan_p1(const int* __restrict__ deg,
                                                 int* __restrict__ bsum)
{
  __shared__ int wsum[4];
  int base = blockIdx.x * 1024 + threadIdx.x * 4;
  int s = 0;
  #pragma unroll
  for (int j = 0; j < 4; ++j) { int i = base + j; if (i < NNODES) s += deg[i]; }
  for (int off = 32; off; off >>= 1) s += __shfl_down(s, off, 64);
  if ((threadIdx.x & 63) == 0) wsum[threadIdx.x >> 6] = s;
  __syncthreads();
  if (threadIdx.x == 0) bsum[blockIdx.x] = wsum[0] + wsum[1] + wsum[2] + wsum[3];
}

__global__ void k_scan_p2(const int* __restrict__ bsum, int* __restrict__ boff,
                          int* __restrict__ row_ptr, int nb)
{
  __shared__ int tmp[128];
  int t = threadIdx.x;
  tmp[t] = (t < nb) ? bsum[t] : 0;
  __syncthreads();
  if (t == 0) {
    int r = 0;
    for (int i = 0; i < nb; ++i) { int v = tmp[i]; boff[i] = r; r += v; }
    row_ptr[NNODES] = r;
  }
}

__global__ __launch_bounds__(256) void k_scan_p3(
    const int* __restrict__ deg, const int* __restrict__ boff,
    int* __restrict__ row_ptr, int* __restrict__ cursor)
{
  __shared__ int tsum[256];
  const int t = threadIdx.x;
  int base = blockIdx.x * 1024 + t * 4;
  int v[4]; int s = 0;
  #pragma unroll
  for (int j = 0; j < 4; ++j) { int i = base + j; v[j] = (i < NNODES) ? deg[i] : 0; s += v[j]; }
  tsum[t] = s;
  __syncthreads();
  for (int off = 1; off < 256; off <<= 1) {
    int y = (t >= off) ? tsum[t - off] : 0;
    __syncthreads();
    tsum[t] += y;
    __syncthreads();
  }
  int run = boff[blockIdx.x] + tsum[t] - s;
  #pragma unroll
  for (int j = 0; j < 4; ++j) {
    int i = base + j;
    if (i < NNODES) { row_ptr[i] = run; cursor[i] = run; run += v[j]; }
  }
}

__global__ __launch_bounds__(256) void k_scatter(
    const int* __restrict__ g_row, const int* __restrict__ g_col,
    const float* __restrict__ g_val, int* __restrict__ cursor,
    int* __restrict__ col_s, float* __restrict__ val_s) {
  int e = blockIdx.x * 256 + threadIdx.x;
  if (e < NEDGES) {
    int r = g_row[e];
    int p = atomicAdd(&cursor[r], 1);
    col_s[p] = g_col[e];
    val_s[p] = g_val[e];
  }
}

// ---------------------------------------------------------------------------
// SpMM v3: wave per row, 8 edges/iter (2 per lane), branchless 16B gathers.
// ---------------------------------------------------------------------------
template<bool WRITE_BF>
__global__ __launch_bounds__(256) void k_spmm(
    const int* __restrict__ row_ptr, const int* __restrict__ col_s,
    const float* __restrict__ val_s, const bf16* __restrict__ X,
    float* __restrict__ Y, bf16* __restrict__ Yb)
{
  int w = (int)((blockIdx.x * 256u + threadIdx.x) >> 6);
  if (w >= NNODES) return;
  const int lane = threadIdx.x & 63;
  const int eg = lane >> 4;
  const int fg = (lane & 15) * 8;
  const int s = row_ptr[w], e = row_ptr[w + 1];

  float acc[8] = {0.f, 0.f, 0.f, 0.f, 0.f, 0.f, 0.f, 0.f};
  for (int i = s; i < e; i += 8) {
    int i0 = i + eg, i1 = i + 4 + eg;
    int   c0 = 0,  c1 = 0;
    float v0 = 0.f, v1 = 0.f;
    if (i0 < e) { c0 = col_s[i0]; v0 = val_s[i0]; }
    if (i1 < e) { c1 = col_s[i1]; v1 = val_s[i1]; }
    short8v x0 = *(const short8v*)&X[(size_t)c0 * 128 + fg];
    short8v x1 = *(const short8v*)&X[(size_t)c1 * 128 + fg];
    #pragma unroll
    for (int j = 0; j < 8; ++j)
      acc[j] += v0 * b2f_(x0[j]) + v1 * b2f_(x1[j]);
  }
  #pragma unroll
  for (int j = 0; j < 8; ++j) {
    acc[j] += __shfl_xor(acc[j], 16, 64);
    acc[j] += __shfl_xor(acc[j], 32, 64);
  }
  if (lane < 16) {
    float4 o0 = make_float4(acc[0], acc[1], acc[2], acc[3]);
    float4 o1 = make_float4(acc[4], acc[5], acc[6], acc[7]);
    *(float4*)&Y[(size_t)w * 128 + fg]     = o0;
    *(float4*)&Y[(size_t)w * 128 + fg + 4] = o1;
    if (WRITE_BF) {
      short8v ob;
      #pragma unroll
      for (int j = 0; j < 8; ++j) {
        __hip_bfloat16 h = __float2bfloat16(acc[j]);
        ob[j] = *(short*)&h;
      }
      *(short8v*)&Yb[(size_t)w * 128 + fg] = ob;
    }
  }
}

// ---------------------------------------------------------------------------
// Gather v2: 2 output rows per wave, float4 (16B) per lane, fused l2norm.
// ---------------------------------------------------------------------------
__global__ __launch_bounds__(256) void k_gather(
    const float* __restrict__ s1, const float* __restrict__ s2,
    const int* __restrict__ i0, const int* __restrict__ i1,
    const int* __restrict__ i2, const int* __restrict__ i3,
    float* __restrict__ out)
{
  long wid = ((long)blockIdx.x * 256 + threadIdx.x) >> 6;   // 0..399999
  int lane = threadIdx.x & 63;
  long gw = wid * 2 + (lane >> 5);                          // 0..799999
  int fl = (lane & 31) * 4;
  int o   = (int)(gw / 200000);
  int rem = (int)(gw % 200000);
  int l = rem / 100000;
  int i = rem % 100000;
  const int* idx = (o == 0) ? i0 : (o == 1) ? i1 : (o == 2) ? i2 : i3;
  int node = idx[i];
  const float* src = (l == 0) ? s1 : s2;
  float4 v = *(const float4*)&src[(size_t)node * 128 + fl];
  float ss = v.x * v.x + v.y * v.y + v.z * v.z + v.w * v.w;
  #pragma unroll
  for (int off = 1; off < 32; off <<= 1) ss += __shfl_xor(ss, off, 64);
  float inv = 1.0f / fmaxf(sqrtf(ss), 1e-12f);
  float4 ov = make_float4(v.x * inv, v.y * inv, v.z * inv, v.w * inv);
  *(float4*)&out[gw * 128 + fl] = ov;
}

__global__ void k_loss_final(const float* __restrict__ loss_acc, float* __restrict__ out) {
  if (threadIdx.x == 0)
    out[102400000] = loss_acc[0] * (1.0f / 50000000.0f);
}

// ---------------------------------------------------------------------------
extern "C" void kernel_launch(void* const* d_in, const int* in_sizes, int n_in,
                              void* d_out, int out_size, void* d_ws, size_t ws_size,
                              hipStream_t stream)
{
  const float* emb_attr = (const float*)d_in[0];
  const float* emb_node = (const float*)d_in[1];
  const float* W0 = (const float*)d_in[2];
  const float* b0 = (const float*)d_in[3];
  const float* W1 = (const float*)d_in[4];
  const float* b1 = (const float*)d_in[5];
  const float* H  = (const float*)d_in[6];
  const float* g_val = (const float*)d_in[7];
  const int* g_row = (const int*)d_in[8];
  const int* g_col = (const int*)d_in[9];
  const int* pos_src = (const int*)d_in[10];
  const int* pos_dst = (const int*)d_in[11];
  const int* neg_src = (const int*)d_in[12];
  const int* neg_dst = (const int*)d_in[13];
  float* out = (float*)d_out;

  const size_t NF = 12800000;
  const int NB = (NNODES + 1023) / 1024;               // 98 scan blocks

  char* base = (char*)d_out;
  bf16*  embn_bf = (bf16*)base;                        // 25.6 MB
  bf16*  Hacc_bf = embn_bf + NF;                       // 25.6 MB
  bf16*  y_bf    = Hacc_bf + NF;                       // 25.6 MB
  bf16*  s1_bf   = y_bf + NF;                          // 25.6 MB
  bf16*  W0t_bf  = s1_bf + NF;                         // 64 KB
  bf16*  W1t_bf  = W0t_bf + 32768;                     // 32 KB
  bf16*  attr_bf = W1t_bf + 16384;                     // 125 KB
  int*   row_ptr  = (int*)(attr_bf + 64000);
  int*   deg      = row_ptr + 100004;
  int*   cursor   = deg + 100000;
  int*   hcnt     = cursor + 100000;
  int*   bsum     = hcnt + 100000;                     // 128
  int*   boff     = bsum + 128;                        // 128
  int*   col_s    = boff + 128;                        // 3.2M
  int*   hattr    = col_s + 3200000;                   // 1M
  int*   hnode    = hattr + HCAP;                      // 1M
  int*   hslot    = hnode + HCAP;                      // 3.2M
  float* val_s    = (float*)(hslot + NNODES * HSLOTS); // 3.2M

  float* s1 = (float*)d_ws;                            // 51.2 MB
  float* s2 = s1 + NF;                                 // 51.2 MB
  float* loss_acc = s2 + NF;                           // [0]=loss, [1]=nz_ctr
  int*   nz_ctr = (int*)loss_acc + 1;

  hipMemsetAsync(loss_acc, 0, 16, stream);
  hipMemsetAsync(deg, 0, NNODES * sizeof(int), stream);
  hipMemsetAsync(hcnt, 0, NNODES * sizeof(int), stream);

  // --- bf16 conversions ---
  k_cvt_bf<<<12500, 256, 0, stream>>>(emb_node, embn_bf, (int)NF);
  k_cvt_small<<<442, 256, 0, stream>>>(W0, W1, emb_attr, W0t_bf, W1t_bf, attr_bf);

  // --- single-pass sparse H extraction ---
  dim3 hgrid(NB, NATTRI);
  k_hnz_single<<<hgrid, 256, 0, stream>>>(H, hcnt, hslot, hattr, hnode, nz_ctr);
  k_hacc_sparse<<<NNODES / 4, 256, 0, stream>>>(hcnt, hslot, emb_attr, Hacc_bf);

  // --- loss: MFMA base + flat sparse correction ---
  dim3 lgrid((NNODES + 127) / 128, 4);
  k_loss_mfma<<<lgrid, 256, 0, stream>>>(embn_bf, attr_bf, loss_acc);
  k_loss_corr_flat<<<4096, 256, 0, stream>>>(hnode, hattr, nz_ctr, emb_attr, emb_node, loss_acc);

  // --- edge CSR ---
  k_hist<<<(NEDGES + 255) / 256, 256, 0, stream>>>(g_row, deg);
  k_scan_p1<<<NB, 256, 0, stream>>>(deg, bsum);
  k_scan_p2<<<1, 128, 0, stream>>>(bsum, boff, row_ptr, NB);
  k_scan_p3<<<NB, 256, 0, stream>>>(deg, boff, row_ptr, cursor);
  k_scatter<<<(NEDGES + 255) / 256, 256, 0, stream>>>(g_row, g_col, g_val, cursor, col_s, val_s);

  // --- GNN layers ---
  const int ggrid = (NNODES + 127) / 128;   // 782
  k_gemm_mfma<256><<<ggrid, 256, 0, stream>>>(embn_bf, Hacc_bf, W0t_bf, b0, y_bf);
  k_spmm<true><<<(NNODES * 64) / 256, 256, 0, stream>>>(row_ptr, col_s, val_s, y_bf, s1, s1_bf);
  k_gemm_mfma<128><<<ggrid, 256, 0, stream>>>(s1_bf, (const bf16*)nullptr, W1t_bf, b1, y_bf);
  k_spmm<false><<<(NNODES * 64) / 256, 256, 0, stream>>>(row_ptr, col_s, val_s, y_bf, s2, (bf16*)nullptr);

  // --- outputs ---
  k_gather<<<100000, 256, 0, stream>>>(s1, s2, pos_src, pos_dst, neg_src, neg_dst, out);
  k_loss_final<<<1, 64, 0, stream>>>(loss_acc, out);
}

// Round 16
// 1151.745 us; speedup vs baseline: 4.5311x; 4.5311x over previous
//
#include <hip/hip_runtime.h>
#include <hip/hip_bf16.h>

#define NFEAT   128
#define NATTRI  500
#define NNODES  100000
#define NEDGES  3200000
#define HCAP    1000000   // nz list capacity (expected ~500K)

typedef __hip_bfloat16 bf16;
typedef __attribute__((ext_vector_type(8))) short short8v;
typedef __attribute__((ext_vector_type(4))) float f32x4;

__device__ __forceinline__ float sigmoidf_(float x) { return 1.0f / (1.0f + __expf(-x)); }
__device__ __forceinline__ float b2f_(short u) {
  return __uint_as_float(((unsigned)(unsigned short)u) << 16);
}

// ---------------------------------------------------------------------------
// f32 -> bf16 cast, 4 elems/thread.
// ---------------------------------------------------------------------------
__global__ __launch_bounds__(256) void k_cvt_bf(const float* __restrict__ src,
                                                bf16* __restrict__ dst, int n)
{
  int i = (blockIdx.x * 256 + threadIdx.x) * 4;
  if (i >= n) return;
  float4 v = *(const float4*)&src[i];
  __hip_bfloat162 a, b;
  a.x = __float2bfloat16(v.x); a.y = __float2bfloat16(v.y);
  b.x = __float2bfloat16(v.z); b.y = __float2bfloat16(v.w);
  *(__hip_bfloat162*)&dst[i]     = a;
  *(__hip_bfloat162*)&dst[i + 2] = b;
}

// ---------------------------------------------------------------------------
// Small conversions: W0t[128][256], W1t[128][128], attr_bf[500][128].
// ---------------------------------------------------------------------------
__global__ __launch_bounds__(256) void k_cvt_small(
    const float* __restrict__ W0, const float* __restrict__ W1,
    const float* __restrict__ emb_attr,
    bf16* __restrict__ W0t, bf16* __restrict__ W1t, bf16* __restrict__ attrb)
{
  int i = blockIdx.x * 256 + threadIdx.x;
  if (i < 32768) {
    int n = i >> 8, k = i & 255;
    W0t[i] = __float2bfloat16(W0[k * 128 + n]);
  } else if (i < 49152) {
    int j = i - 32768;
    int n = j >> 7, k = j & 127;
    W1t[j] = __float2bfloat16(W1[k * 128 + n]);
  } else if (i < 113152) {
    int j = i - 49152;
    attrb[j] = __float2bfloat16(emb_attr[j]);
  }
}

// ---------------------------------------------------------------------------
// H nonzero extraction (two-pass, distributed per-node cursors)
// ---------------------------------------------------------------------------
__global__ __launch_bounds__(256) void k_hnz_count(
    const float* __restrict__ H, int* __restrict__ hcnt)
{
  const int a   = blockIdx.y;
  const int off = blockIdx.x * 1024 + threadIdx.x * 4;
  if (off + 3 < NNODES) {
    float4 h4 = *(const float4*)&H[(size_t)a * NNODES + off];
    if (h4.x > 0.5f) atomicAdd(&hcnt[off + 0], 1);
    if (h4.y > 0.5f) atomicAdd(&hcnt[off + 1], 1);
    if (h4.z > 0.5f) atomicAdd(&hcnt[off + 2], 1);
    if (h4.w > 0.5f) atomicAdd(&hcnt[off + 3], 1);
  } else {
    for (int j = 0; j < 4; ++j) {
      int n = off + j;
      if (n < NNODES && H[(size_t)a * NNODES + n] > 0.5f) atomicAdd(&hcnt[n], 1);
    }
  }
}

__global__ __launch_bounds__(256) void k_hnz_place(
    const float* __restrict__ H, int* __restrict__ hcursor,
    int* __restrict__ hattr, int* __restrict__ hnode)
{
  const int a   = blockIdx.y;
  const int off = blockIdx.x * 1024 + threadIdx.x * 4;
  if (off + 3 < NNODES) {
    float4 h4 = *(const float4*)&H[(size_t)a * NNODES + off];
    float hv[4] = {h4.x, h4.y, h4.z, h4.w};
    #pragma unroll
    for (int j = 0; j < 4; ++j) {
      if (hv[j] > 0.5f) {
        int pos = atomicAdd(&hcursor[off + j], 1);
        if (pos < HCAP) { hattr[pos] = a; hnode[pos] = off + j; }
      }
    }
  } else {
    for (int j = 0; j < 4; ++j) {
      int n = off + j;
      if (n < NNODES && H[(size_t)a * NNODES + n] > 0.5f) {
        int pos = atomicAdd(&hcursor[n], 1);
        if (pos < HCAP) { hattr[pos] = a; hnode[pos] = n; }
      }
    }
  }
}

// ---------------------------------------------------------------------------
// Hacc[n] = sum of emb_attr rows over H-nonzeros -> bf16.
// ---------------------------------------------------------------------------
__global__ __launch_bounds__(256) void k_hacc_sparse(
    const int* __restrict__ hrow_ptr, const int* __restrict__ hattr,
    const float* __restrict__ emb_attr, bf16* __restrict__ Haccb)
{
  int n = blockIdx.x * 4 + (threadIdx.x >> 6);
  if (n >= NNODES) return;
  int lane = threadIdx.x & 63;
  int s = hrow_ptr[n], e = min(hrow_ptr[n + 1], HCAP);
  int f = lane * 2;
  float ax = 0.f, ay = 0.f;
  for (int i = s; i < e; ++i) {
    int a = hattr[i];
    float2 v = *(const float2*)&emb_attr[a * 128 + f];
    ax += v.x; ay += v.y;
  }
  __hip_bfloat162 o;
  o.x = __float2bfloat16(ax); o.y = __float2bfloat16(ay);
  *(__hip_bfloat162*)&Haccb[(size_t)n * 128 + f] = o;
}

// ---------------------------------------------------------------------------
// MFMA GEMM: Y[n][c] = Xcat@W + b, bf16 out. 128x128 tile, 4 waves.
// ---------------------------------------------------------------------------
template<int KTOT>
__global__ __launch_bounds__(256) void k_gemm_mfma(
    const bf16* __restrict__ X0, const bf16* __restrict__ X1,
    const bf16* __restrict__ Wt, const float* __restrict__ bias,
    bf16* __restrict__ Y)
{
  __shared__ __align__(16) short sX[128 * 72];
  __shared__ __align__(16) short sW[128 * 72];
  const int t = threadIdx.x;
  const int w = t >> 6, l = t & 63;
  const int lrow = l & 15, lk = (l >> 4) * 8;
  const int r0 = blockIdx.x * 128;

  f32x4 acc[2][8];
  #pragma unroll
  for (int m2 = 0; m2 < 2; ++m2)
    #pragma unroll
    for (int nf = 0; nf < 8; ++nf)
      acc[m2][nf] = (f32x4){0.f, 0.f, 0.f, 0.f};

  for (int kc = 0; kc < KTOT; kc += 64) {
    __syncthreads();
    {
      int row = t >> 1, ks = (t & 1) * 32;
      int n = r0 + row;
      int gk = kc + ks;
      const bf16* src = X0; int k0 = gk;
      if (KTOT == 256 && gk >= 128) { src = X1; k0 = gk - 128; }
      short* d = &sX[row * 72 + ks];
      if (n < NNODES) {
        const short* p = (const short*)&src[(size_t)n * 128 + k0];
        #pragma unroll
        for (int i = 0; i < 4; ++i) *(short8v*)&d[i * 8] = *(const short8v*)&p[i * 8];
      } else {
        short8v z = (short8v){0,0,0,0,0,0,0,0};
        #pragma unroll
        for (int i = 0; i < 4; ++i) *(short8v*)&d[i * 8] = z;
      }
    }
    {
      int nrow = t >> 1, ks = (t & 1) * 32;
      const short* p = (const short*)&Wt[(size_t)nrow * KTOT + kc + ks];
      short* d = &sW[nrow * 72 + ks];
      #pragma unroll
      for (int i = 0; i < 4; ++i) *(short8v*)&d[i * 8] = *(const short8v*)&p[i * 8];
    }
    __syncthreads();
    #pragma unroll
    for (int kf = 0; kf < 2; ++kf) {
      short8v a0 = *(const short8v*)&sX[(w * 32 +      lrow) * 72 + kf * 32 + lk];
      short8v a1 = *(const short8v*)&sX[(w * 32 + 16 + lrow) * 72 + kf * 32 + lk];
      #pragma unroll
      for (int nf = 0; nf < 8; ++nf) {
        short8v b = *(const short8v*)&sW[(nf * 16 + lrow) * 72 + kf * 32 + lk];
        acc[0][nf] = __builtin_amdgcn_mfma_f32_16x16x32_bf16(a0, b, acc[0][nf], 0, 0, 0);
        acc[1][nf] = __builtin_amdgcn_mfma_f32_16x16x32_bf16(a1, b, acc[1][nf], 0, 0, 0);
      }
    }
  }
  #pragma unroll
  for (int m2 = 0; m2 < 2; ++m2) {
    int rbase = r0 + w * 32 + m2 * 16 + (l >> 4) * 4;
    #pragma unroll
    for (int nf = 0; nf < 8; ++nf) {
      int col = nf * 16 + lrow;
      float bv = bias[col];
      #pragma unroll
      for (int ri = 0; ri < 4; ++ri) {
        int grow = rbase + ri;
        if (grow < NNODES)
          Y[(size_t)grow * 128 + col] = __float2bfloat16(acc[m2][nf][ri] + bv);
      }
    }
  }
}

// ---------------------------------------------------------------------------
// MFMA loss base: sum 0.1*sigmoid(emb_node @ emb_attr^T)^2 over all pairs.
// ---------------------------------------------------------------------------
__global__ __launch_bounds__(256) void k_loss_mfma(
    const bf16* __restrict__ Xb, const bf16* __restrict__ Ab,
    float* __restrict__ loss_acc)
{
  __shared__ __align__(16) short sX[128 * 72];
  __shared__ __align__(16) short sW[128 * 72];
  __shared__ float red[4];
  const int t = threadIdx.x;
  const int w = t >> 6, l = t & 63;
  const int lrow = l & 15, lk = (l >> 4) * 8;
  const int r0 = blockIdx.x * 128;
  const int a0 = blockIdx.y * 128;

  f32x4 acc[2][8];
  #pragma unroll
  for (int m2 = 0; m2 < 2; ++m2)
    #pragma unroll
    for (int nf = 0; nf < 8; ++nf)
      acc[m2][nf] = (f32x4){0.f, 0.f, 0.f, 0.f};

  for (int kc = 0; kc < 128; kc += 64) {
    __syncthreads();
    {
      int row = t >> 1, ks = (t & 1) * 32;
      int n = r0 + row;
      short* d = &sX[row * 72 + ks];
      if (n < NNODES) {
        const short* p = (const short*)&Xb[(size_t)n * 128 + kc + ks];
        #pragma unroll
        for (int i = 0; i < 4; ++i) *(short8v*)&d[i * 8] = *(const short8v*)&p[i * 8];
      } else {
        short8v z = (short8v){0,0,0,0,0,0,0,0};
        #pragma unroll
        for (int i = 0; i < 4; ++i) *(short8v*)&d[i * 8] = z;
      }
    }
    {
      int nrow = t >> 1, ks = (t & 1) * 32;
      int a = a0 + nrow;
      short* d = &sW[nrow * 72 + ks];
      if (a < NATTRI) {
        const short* p = (const short*)&Ab[(size_t)a * 128 + kc + ks];
        #pragma unroll
        for (int i = 0; i < 4; ++i) *(short8v*)&d[i * 8] = *(const short8v*)&p[i * 8];
      } else {
        short8v z = (short8v){0,0,0,0,0,0,0,0};
        #pragma unroll
        for (int i = 0; i < 4; ++i) *(short8v*)&d[i * 8] = z;
      }
    }
    __syncthreads();
    #pragma unroll
    for (int kf = 0; kf < 2; ++kf) {
      short8v av0 = *(const short8v*)&sX[(w * 32 +      lrow) * 72 + kf * 32 + lk];
      short8v av1 = *(const short8v*)&sX[(w * 32 + 16 + lrow) * 72 + kf * 32 + lk];
      #pragma unroll
      for (int nf = 0; nf < 8; ++nf) {
        short8v b = *(const short8v*)&sW[(nf * 16 + lrow) * 72 + kf * 32 + lk];
        acc[0][nf] = __builtin_amdgcn_mfma_f32_16x16x32_bf16(av0, b, acc[0][nf], 0, 0, 0);
        acc[1][nf] = __builtin_amdgcn_mfma_f32_16x16x32_bf16(av1, b, acc[1][nf], 0, 0, 0);
      }
    }
  }
  float lacc = 0.f;
  #pragma unroll
  for (int m2 = 0; m2 < 2; ++m2) {
    int rbase = r0 + w * 32 + m2 * 16 + (l >> 4) * 4;
    #pragma unroll
    for (int nf = 0; nf < 8; ++nf) {
      int col = a0 + nf * 16 + lrow;
      if (col < NATTRI) {
        #pragma unroll
        for (int ri = 0; ri < 4; ++ri) {
          int grow = rbase + ri;
          if (grow < NNODES) {
            float s = sigmoidf_(acc[m2][nf][ri]);
            lacc += 0.1f * s * s;
          }
        }
      }
    }
  }
  for (int off = 32; off; off >>= 1) lacc += __shfl_xor(lacc, off, 64);
  if (l == 0) red[w] = lacc;
  __syncthreads();
  if (t == 0) atomicAdd(loss_acc, red[0] + red[1] + red[2] + red[3]);
}

// ---------------------------------------------------------------------------
// Flat loss correction: wave per nz entry, grid-stride.
// ---------------------------------------------------------------------------
__global__ __launch_bounds__(256) void k_loss_corr_flat(
    const int* __restrict__ hnode, const int* __restrict__ hattr,
    const int* __restrict__ hrow_ptr,
    const float* __restrict__ emb_attr, const float* __restrict__ emb_node,
    float* __restrict__ loss_acc)
{
  __shared__ float red[4];
  const int total = min(hrow_ptr[NNODES], HCAP);
  const int lane = threadIdx.x & 63;
  const int wv = (blockIdx.x * 256 + threadIdx.x) >> 6;
  const int nw = gridDim.x * 4;
  float part = 0.f;
  for (int i = wv; i < total; i += nw) {
    int n = hnode[i];
    int a = hattr[i];
    float2 x = *(const float2*)&emb_node[(size_t)n * 128 + lane * 2];
    float2 w = *(const float2*)&emb_attr[a * 128 + lane * 2];
    float d = x.x * w.x + x.y * w.y;
    for (int off = 32; off; off >>= 1) d += __shfl_xor(d, off, 64);
    if (lane == 0) {
      float sg = sigmoidf_(d);
      float om = 1.f - sg;
      part += 2.0f * om * om - 0.1f * sg * sg;
    }
  }
  if (lane == 0) red[threadIdx.x >> 6] = part;
  __syncthreads();
  if (threadIdx.x == 0) atomicAdd(loss_acc, red[0] + red[1] + red[2] + red[3]);
}

// ---------------------------------------------------------------------------
// Edge CSR build: hist + 3-phase parallel scan + scatter
// ---------------------------------------------------------------------------
__global__ __launch_bounds__(256) void k_hist(const int* __restrict__ g_row,
                                              int* __restrict__ deg) {
  int e = blockIdx.x * 256 + threadIdx.x;
  if (e < NEDGES) atomicAdd(&deg[g_row[e]], 1);
}

__global__ __launch_bounds__(256) void k_scan_p1(const int* __restrict__ deg,
                                                 int* __restrict__ bsum)
{
  __shared__ int wsum[4];
  int base = blockIdx.x * 1024 + threadIdx.x * 4;
  int s = 0;
  #pragma unroll
  for (int j = 0; j < 4; ++j) { int i = base + j; if (i < NNODES) s += deg[i]; }
  for (int off = 32; off; off >>= 1) s += __shfl_down(s, off, 64);
  if ((threadIdx.x & 63) == 0) wsum[threadIdx.x >> 6] = s;
  __syncthreads();
  if (threadIdx.x == 0) bsum[blockIdx.x] = wsum[0] + wsum[1] + wsum[2] + wsum[3];
}

__global__ void k_scan_p2(const int* __restrict__ bsum, int* __restrict__ boff,
                          int* __restrict__ row_ptr, int nb)
{
  __shared__ int tmp[128];
  int t = threadIdx.x;
  tmp[t] = (t < nb) ? bsum[t] : 0;
  __syncthreads();
  if (t == 0) {
    int r = 0;
    for (int i = 0; i < nb; ++i) { int v = tmp[i]; boff[i] = r; r += v; }
    row_ptr[NNODES] = r;
  }
}

__global__ __launch_bounds__(256) void k_scan_p3(
    const int* __restrict__ deg, const int* __restrict__ boff,
    int* __restrict__ row_ptr, int* __restrict__ cursor)
{
  __shared__ int tsum[256];
  const int t = threadIdx.x;
  int base = blockIdx.x * 1024 + t * 4;
  int v[4]; int s = 0;
  #pragma unroll
  for (int j = 0; j < 4; ++j) { int i = base + j; v[j] = (i < NNODES) ? deg[i] : 0; s += v[j]; }
  tsum[t] = s;
  __syncthreads();
  for (int off = 1; off < 256; off <<= 1) {
    int y = (t >= off) ? tsum[t - off] : 0;
    __syncthreads();
    tsum[t] += y;
    __syncthreads();
  }
  int run = boff[blockIdx.x] + tsum[t] - s;
  #pragma unroll
  for (int j = 0; j < 4; ++j) {
    int i = base + j;
    if (i < NNODES) { row_ptr[i] = run; cursor[i] = run; run += v[j]; }
  }
}

__global__ __launch_bounds__(256) void k_scatter(
    const int* __restrict__ g_row, const int* __restrict__ g_col,
    const float* __restrict__ g_val, int* __restrict__ cursor,
    int* __restrict__ col_s, float* __restrict__ val_s) {
  int e = blockIdx.x * 256 + threadIdx.x;
  if (e < NEDGES) {
    int r = g_row[e];
    int p = atomicAdd(&cursor[r], 1);
    col_s[p] = g_col[e];
    val_s[p] = g_val[e];
  }
}

// ---------------------------------------------------------------------------
// SpMM v3: wave per row, 8 edges/iter (2 per lane), branchless 16B gathers.
// ---------------------------------------------------------------------------
template<bool WRITE_BF>
__global__ __launch_bounds__(256) void k_spmm(
    const int* __restrict__ row_ptr, const int* __restrict__ col_s,
    const float* __restrict__ val_s, const bf16* __restrict__ X,
    float* __restrict__ Y, bf16* __restrict__ Yb)
{
  int w = (int)((blockIdx.x * 256u + threadIdx.x) >> 6);
  if (w >= NNODES) return;
  const int lane = threadIdx.x & 63;
  const int eg = lane >> 4;
  const int fg = (lane & 15) * 8;
  const int s = row_ptr[w], e = row_ptr[w + 1];

  float acc[8] = {0.f, 0.f, 0.f, 0.f, 0.f, 0.f, 0.f, 0.f};
  for (int i = s; i < e; i += 8) {
    int i0 = i + eg, i1 = i + 4 + eg;
    int   c0 = 0,  c1 = 0;
    float v0 = 0.f, v1 = 0.f;
    if (i0 < e) { c0 = col_s[i0]; v0 = val_s[i0]; }
    if (i1 < e) { c1 = col_s[i1]; v1 = val_s[i1]; }
    short8v x0 = *(const short8v*)&X[(size_t)c0 * 128 + fg];
    short8v x1 = *(const short8v*)&X[(size_t)c1 * 128 + fg];
    #pragma unroll
    for (int j = 0; j < 8; ++j)
      acc[j] += v0 * b2f_(x0[j]) + v1 * b2f_(x1[j]);
  }
  #pragma unroll
  for (int j = 0; j < 8; ++j) {
    acc[j] += __shfl_xor(acc[j], 16, 64);
    acc[j] += __shfl_xor(acc[j], 32, 64);
  }
  if (lane < 16) {
    float4 o0 = make_float4(acc[0], acc[1], acc[2], acc[3]);
    float4 o1 = make_float4(acc[4], acc[5], acc[6], acc[7]);
    *(float4*)&Y[(size_t)w * 128 + fg]     = o0;
    *(float4*)&Y[(size_t)w * 128 + fg + 4] = o1;
    if (WRITE_BF) {
      short8v ob;
      #pragma unroll
      for (int j = 0; j < 8; ++j) {
        __hip_bfloat16 h = __float2bfloat16(acc[j]);
        ob[j] = *(short*)&h;
      }
      *(short8v*)&Yb[(size_t)w * 128 + fg] = ob;
    }
  }
}

// ---------------------------------------------------------------------------
// Gather v2: 2 output rows per wave, float4 (16B) per lane, fused l2norm.
// ---------------------------------------------------------------------------
__global__ __launch_bounds__(256) void k_gather(
    const float* __restrict__ s1, const float* __restrict__ s2,
    const int* __restrict__ i0, const int* __restrict__ i1,
    const int* __restrict__ i2, const int* __restrict__ i3,
    float* __restrict__ out)
{
  long wid = ((long)blockIdx.x * 256 + threadIdx.x) >> 6;   // 0..399999
  int lane = threadIdx.x & 63;
  long gw = wid * 2 + (lane >> 5);                          // 0..799999
  int fl = (lane & 31) * 4;
  int o   = (int)(gw / 200000);
  int rem = (int)(gw % 200000);
  int l = rem / 100000;
  int i = rem % 100000;
  const int* idx = (o == 0) ? i0 : (o == 1) ? i1 : (o == 2) ? i2 : i3;
  int node = idx[i];
  const float* src = (l == 0) ? s1 : s2;
  float4 v = *(const float4*)&src[(size_t)node * 128 + fl];
  float ss = v.x * v.x + v.y * v.y + v.z * v.z + v.w * v.w;
  #pragma unroll
  for (int off = 1; off < 32; off <<= 1) ss += __shfl_xor(ss, off, 64);
  float inv = 1.0f / fmaxf(sqrtf(ss), 1e-12f);
  float4 ov = make_float4(v.x * inv, v.y * inv, v.z * inv, v.w * inv);
  *(float4*)&out[gw * 128 + fl] = ov;
}

__global__ void k_loss_final(const float* __restrict__ loss_acc, float* __restrict__ out) {
  if (threadIdx.x == 0)
    out[102400000] = loss_acc[0] * (1.0f / 50000000.0f);
}

// ---------------------------------------------------------------------------
extern "C" void kernel_launch(void* const* d_in, const int* in_sizes, int n_in,
                              void* d_out, int out_size, void* d_ws, size_t ws_size,
                              hipStream_t stream)
{
  const float* emb_attr = (const float*)d_in[0];
  const float* emb_node = (const float*)d_in[1];
  const float* W0 = (const float*)d_in[2];
  const float* b0 = (const float*)d_in[3];
  const float* W1 = (const float*)d_in[4];
  const float* b1 = (const float*)d_in[5];
  const float* H  = (const float*)d_in[6];
  const float* g_val = (const float*)d_in[7];
  const int* g_row = (const int*)d_in[8];
  const int* g_col = (const int*)d_in[9];
  const int* pos_src = (const int*)d_in[10];
  const int* pos_dst = (const int*)d_in[11];
  const int* neg_src = (const int*)d_in[12];
  const int* neg_dst = (const int*)d_in[13];
  float* out = (float*)d_out;

  const size_t NF = 12800000;
  const int NB = (NNODES + 1023) / 1024;               // 98 scan blocks

  char* base = (char*)d_out;
  bf16*  embn_bf = (bf16*)base;                        // 25.6 MB
  bf16*  Hacc_bf = embn_bf + NF;                       // 25.6 MB
  bf16*  y_bf    = Hacc_bf + NF;                       // 25.6 MB
  bf16*  s1_bf   = y_bf + NF;                          // 25.6 MB
  bf16*  W0t_bf  = s1_bf + NF;                         // 64 KB
  bf16*  W1t_bf  = W0t_bf + 32768;                     // 32 KB
  bf16*  attr_bf = W1t_bf + 16384;                     // 125 KB
  int*   row_ptr  = (int*)(attr_bf + 64000);
  int*   deg      = row_ptr + 100004;
  int*   cursor   = deg + 100000;
  int*   hrow_ptr = cursor + 100000;
  int*   hcnt     = hrow_ptr + 100004;
  int*   hcursor  = hcnt + 100000;
  int*   bsum     = hcursor + 100000;                  // 128
  int*   boff     = bsum + 128;                        // 128
  int*   col_s    = boff + 128;                        // 3.2M
  int*   hattr    = col_s + 3200000;                   // 1M
  int*   hnode    = hattr + HCAP;                      // 1M
  float* val_s    = (float*)(hnode + HCAP);            // 3.2M

  float* s1 = (float*)d_ws;                            // 51.2 MB
  float* s2 = s1 + NF;                                 // 51.2 MB
  float* loss_acc = s2 + NF;

  hipMemsetAsync(loss_acc, 0, 16, stream);
  hipMemsetAsync(deg, 0, NNODES * sizeof(int), stream);
  hipMemsetAsync(hcnt, 0, NNODES * sizeof(int), stream);

  // --- bf16 conversions ---
  k_cvt_bf<<<12500, 256, 0, stream>>>(emb_node, embn_bf, (int)NF);
  k_cvt_small<<<442, 256, 0, stream>>>(W0, W1, emb_attr, W0t_bf, W1t_bf, attr_bf);

  // --- sparse H extraction (two-pass, distributed cursors) ---
  dim3 hgrid(NB, NATTRI);
  k_hnz_count<<<hgrid, 256, 0, stream>>>(H, hcnt);
  k_scan_p1<<<NB, 256, 0, stream>>>(hcnt, bsum);
  k_scan_p2<<<1, 128, 0, stream>>>(bsum, boff, hrow_ptr, NB);
  k_scan_p3<<<NB, 256, 0, stream>>>(hcnt, boff, hrow_ptr, hcursor);
  k_hnz_place<<<hgrid, 256, 0, stream>>>(H, hcursor, hattr, hnode);
  k_hacc_sparse<<<NNODES / 4, 256, 0, stream>>>(hrow_ptr, hattr, emb_attr, Hacc_bf);

  // --- loss: MFMA base + flat sparse correction ---
  dim3 lgrid((NNODES + 127) / 128, 4);
  k_loss_mfma<<<lgrid, 256, 0, stream>>>(embn_bf, attr_bf, loss_acc);
  k_loss_corr_flat<<<4096, 256, 0, stream>>>(hnode, hattr, hrow_ptr, emb_attr, emb_node, loss_acc);

  // --- edge CSR ---
  k_hist<<<(NEDGES + 255) / 256, 256, 0, stream>>>(g_row, deg);
  k_scan_p1<<<NB, 256, 0, stream>>>(deg, bsum);
  k_scan_p2<<<1, 128, 0, stream>>>(bsum, boff, row_ptr, NB);
  k_scan_p3<<<NB, 256, 0, stream>>>(deg, boff, row_ptr, cursor);
  k_scatter<<<(NEDGES + 255) / 256, 256, 0, stream>>>(g_row, g_col, g_val, cursor, col_s, val_s);

  // --- GNN layers ---
  const int ggrid = (NNODES + 127) / 128;   // 782
  k_gemm_mfma<256><<<ggrid, 256, 0, stream>>>(embn_bf, Hacc_bf, W0t_bf, b0, y_bf);
  k_spmm<true><<<(NNODES * 64) / 256, 256, 0, stream>>>(row_ptr, col_s, val_s, y_bf, s1, s1_bf);
  k_gemm_mfma<128><<<ggrid, 256, 0, stream>>>(s1_bf, (const bf16*)nullptr, W1t_bf, b1, y_bf);
  k_spmm<false><<<(NNODES * 64) / 256, 256, 0, stream>>>(row_ptr, col_s, val_s, y_bf, s2, (bf16*)nullptr);

  // --- outputs ---
  k_gather<<<100000, 256, 0, stream>>>(s1, s2, pos_src, pos_dst, neg_src, neg_dst, out);
  k_loss_final<<<1, 64, 0, stream>>>(loss_acc, out);
}